// Round 3
// baseline (158.868 us; speedup 1.0000x reference)
//
#include <hip/hip_runtime.h>
#include <stdint.h>

// random_masking: out = input, except channels {0,10,...,90} of each batch are
// replaced with jax.random.normal(jax.random.key(1), (4, 10, 512*512)).
// PRNG path (verified R1, absmax 1.5e-2 vs 1.08e-1 threshold): partitionable
// Threefry-2x32 + XLA Giles erfinv. DO NOT change numerics.
//
// R3 structure: every block identical = one 2048-f4 column slice of a
// 10-channel group (1 noise + 9 copy). Noise VALU hides under first copy
// loads; copies double-buffered 8 f4 deep. 1280 blocks = exactly 5/CU.

typedef float f32x4 __attribute__((ext_vector_type(4)));

__device__ __forceinline__ uint32_t rotl32(uint32_t v, int r) {
    return (v << r) | (v >> (32 - r));
}

// Threefry-2x32, key = (0, 1)  [jax.random.key(1)]
__device__ __forceinline__ void threefry2x32_key01(uint32_t x0, uint32_t x1,
                                                   uint32_t& o0, uint32_t& o1) {
    const uint32_t ks0 = 0u;
    const uint32_t ks1 = 1u;
    const uint32_t ks2 = 0x1BD11BDAu ^ ks0 ^ ks1;  // 0x1BD11BDB
    x0 += ks0; x1 += ks1;
#define TF_R(r) { x0 += x1; x1 = rotl32(x1, (r)); x1 ^= x0; }
    TF_R(13) TF_R(15) TF_R(26) TF_R(6)
    x0 += ks1; x1 += ks2 + 1u;
    TF_R(17) TF_R(29) TF_R(16) TF_R(24)
    x0 += ks2; x1 += ks0 + 2u;
    TF_R(13) TF_R(15) TF_R(26) TF_R(6)
    x0 += ks0; x1 += ks1 + 3u;
    TF_R(17) TF_R(29) TF_R(16) TF_R(24)
    x0 += ks1; x1 += ks2 + 4u;
    TF_R(13) TF_R(15) TF_R(26) TF_R(6)
    x0 += ks2; x1 += ks0 + 5u;
#undef TF_R
    o0 = x0; o1 = x1;
}

// XLA f32 ErfInv (Giles polynomial) — identical coefficients to xla math.cc
__device__ __forceinline__ float erfinv_xla_f32(float x) {
    float w = -log1pf(-x * x);
    float p;
    if (w < 5.0f) {
        w = w - 2.5f;
        p = 2.81022636e-08f;
        p = fmaf(p, w, 3.43273939e-07f);
        p = fmaf(p, w, -3.5233877e-06f);
        p = fmaf(p, w, -4.39150654e-06f);
        p = fmaf(p, w, 0.00021858087f);
        p = fmaf(p, w, -0.00125372503f);
        p = fmaf(p, w, -0.00417768164f);
        p = fmaf(p, w, 0.246640727f);
        p = fmaf(p, w, 1.50140941f);
    } else {
        w = sqrtf(w) - 3.0f;
        p = -0.000200214257f;
        p = fmaf(p, w, 0.000100950558f);
        p = fmaf(p, w, 0.00134934322f);
        p = fmaf(p, w, -0.00367342844f);
        p = fmaf(p, w, 0.00573950773f);
        p = fmaf(p, w, -0.0076224613f);
        p = fmaf(p, w, 0.00943887047f);
        p = fmaf(p, w, 1.00167406f);
        p = fmaf(p, w, 2.83297682f);
    }
    return p * x;
}

// bits -> uniform(nextafter(-1,0), 1) -> sqrt(2)*erfinv(u), matching JAX normal()
__device__ __forceinline__ float bits_to_normal(uint32_t bits) {
    float f = __uint_as_float((bits >> 9) | 0x3F800000u) - 1.0f;  // [0, 1)
    const float lo = __uint_as_float(0xBF7FFFFFu);                // nextafter(-1f, 0)
    float u = f * 2.0f + lo;   // exact: f*2 is a pow2 scale, sum representable
    u = fmaxf(lo, u);
    const float sqrt2 = __uint_as_float(0x3FB504F3u);             // float32(sqrt(2))
    return sqrt2 * erfinv_xla_f32(u);
}

// Geometry: (4,100,512,512) f32. Channel = 65536 f4. Group = 10 channels
// (cb0 = grp*10 is the noise channel; cb0+1..cb0+9 are copies).
// Tile = 2048 f4 => 32 tiles/channel-group column, 40 groups => 1280 blocks.
constexpr uint32_t NBLOCKS = 40u * 32u;

__global__ __launch_bounds__(256) void random_masking_kernel(
        const f32x4* __restrict__ in, f32x4* __restrict__ out) {
    const uint32_t bid  = blockIdx.x;
    const uint32_t grp  = bid >> 5;                  // 0..39
    const uint32_t tile = bid & 31u;
    const uint32_t cb0  = grp * 10u;                 // noise channel (b*100 + c)
    const uint32_t off  = (tile << 11) + threadIdx.x;  // f4 offset in channel

    // ---- issue first copy channel's loads (ch=1) before noise compute ----
    f32x4 buf[2][8];
#pragma unroll
    for (int k = 0; k < 8; ++k)
        buf[1][k] = __builtin_nontemporal_load(in + ((cb0 + 1) << 16) + off + k * 256);

    // ---- noise channel: pure VALU, overlaps the outstanding loads ----
    {
        const uint32_t b = cb0 / 100u;
        const uint32_t s = (cb0 % 100u) / 10u;
        const uint32_t jch = (b * 10u + s) << 18;    // channel base in noise array
#pragma unroll
        for (int k = 0; k < 8; ++k) {
            const uint32_t j = jch + ((off + k * 256u) << 2);
            f32x4 o;
#pragma unroll
            for (int e = 0; e < 4; ++e) {
                uint32_t y0, y1;
                threefry2x32_key01(0u, j + (uint32_t)e, y0, y1);
                o[e] = bits_to_normal(y0 ^ y1);
            }
            __builtin_nontemporal_store(o, out + (cb0 << 16) + off + k * 256);
        }
    }

    // ---- 9 copy channels, double-buffered ----
#pragma unroll
    for (int ch = 1; ch <= 9; ++ch) {
        if (ch < 9) {
#pragma unroll
            for (int k = 0; k < 8; ++k)
                buf[(ch + 1) & 1][k] =
                    __builtin_nontemporal_load(in + ((cb0 + ch + 1) << 16) + off + k * 256);
        }
#pragma unroll
        for (int k = 0; k < 8; ++k)
            __builtin_nontemporal_store(buf[ch & 1][k],
                                        out + ((cb0 + ch) << 16) + off + k * 256);
    }
}

extern "C" void kernel_launch(void* const* d_in, const int* in_sizes, int n_in,
                              void* d_out, int out_size, void* d_ws, size_t ws_size,
                              hipStream_t stream) {
    const f32x4* in = reinterpret_cast<const f32x4*>(d_in[0]);
    f32x4* out = reinterpret_cast<f32x4*>(d_out);
    random_masking_kernel<<<NBLOCKS, 256, 0, stream>>>(in, out);
}

// Round 4
// 152.563 us; speedup vs baseline: 1.0413x; 1.0413x over previous
//
#include <hip/hip_runtime.h>
#include <stdint.h>

// random_masking: out = input, except channels {0,10,...,90} of each batch are
// replaced with jax.random.normal(jax.random.key(1), (4, 10, 512*512)).
// PRNG path (verified R1, absmax 1.5e-2 vs 1.08e-1 threshold): partitionable
// Threefry-2x32 + XLA Giles erfinv. DO NOT change numerics.
//
// R4 structure: homogeneous 10-channel group blocks (R3 geometry) but noise is
// WOVEN one float4 per copy-channel iteration, sitting between load-issue and
// the vmcnt-gated stores so the ~19us of chip-wide PRNG VALU hides under the
// copy stream (R3's mistake: all noise up-front, memory pipe idled ~12us).
// 1280 blocks = exactly 5/CU co-resident (launch_bounds caps VGPR at 102).

typedef float f32x4 __attribute__((ext_vector_type(4)));

__device__ __forceinline__ uint32_t rotl32(uint32_t v, int r) {
    return (v << r) | (v >> (32 - r));
}

// Threefry-2x32, key = (0, 1)  [jax.random.key(1)]
__device__ __forceinline__ void threefry2x32_key01(uint32_t x0, uint32_t x1,
                                                   uint32_t& o0, uint32_t& o1) {
    const uint32_t ks0 = 0u;
    const uint32_t ks1 = 1u;
    const uint32_t ks2 = 0x1BD11BDAu ^ ks0 ^ ks1;  // 0x1BD11BDB
    x0 += ks0; x1 += ks1;
#define TF_R(r) { x0 += x1; x1 = rotl32(x1, (r)); x1 ^= x0; }
    TF_R(13) TF_R(15) TF_R(26) TF_R(6)
    x0 += ks1; x1 += ks2 + 1u;
    TF_R(17) TF_R(29) TF_R(16) TF_R(24)
    x0 += ks2; x1 += ks0 + 2u;
    TF_R(13) TF_R(15) TF_R(26) TF_R(6)
    x0 += ks0; x1 += ks1 + 3u;
    TF_R(17) TF_R(29) TF_R(16) TF_R(24)
    x0 += ks1; x1 += ks2 + 4u;
    TF_R(13) TF_R(15) TF_R(26) TF_R(6)
    x0 += ks2; x1 += ks0 + 5u;
#undef TF_R
    o0 = x0; o1 = x1;
}

// XLA f32 ErfInv (Giles polynomial) — identical coefficients to xla math.cc
__device__ __forceinline__ float erfinv_xla_f32(float x) {
    float w = -log1pf(-x * x);
    float p;
    if (w < 5.0f) {
        w = w - 2.5f;
        p = 2.81022636e-08f;
        p = fmaf(p, w, 3.43273939e-07f);
        p = fmaf(p, w, -3.5233877e-06f);
        p = fmaf(p, w, -4.39150654e-06f);
        p = fmaf(p, w, 0.00021858087f);
        p = fmaf(p, w, -0.00125372503f);
        p = fmaf(p, w, -0.00417768164f);
        p = fmaf(p, w, 0.246640727f);
        p = fmaf(p, w, 1.50140941f);
    } else {
        w = sqrtf(w) - 3.0f;
        p = -0.000200214257f;
        p = fmaf(p, w, 0.000100950558f);
        p = fmaf(p, w, 0.00134934322f);
        p = fmaf(p, w, -0.00367342844f);
        p = fmaf(p, w, 0.00573950773f);
        p = fmaf(p, w, -0.0076224613f);
        p = fmaf(p, w, 0.00943887047f);
        p = fmaf(p, w, 1.00167406f);
        p = fmaf(p, w, 2.83297682f);
    }
    return p * x;
}

// bits -> uniform(nextafter(-1,0), 1) -> sqrt(2)*erfinv(u), matching JAX normal()
__device__ __forceinline__ float bits_to_normal(uint32_t bits) {
    float f = __uint_as_float((bits >> 9) | 0x3F800000u) - 1.0f;  // [0, 1)
    const float lo = __uint_as_float(0xBF7FFFFFu);                // nextafter(-1f, 0)
    float u = f * 2.0f + lo;   // exact: f*2 is a pow2 scale, sum representable
    u = fmaxf(lo, u);
    const float sqrt2 = __uint_as_float(0x3FB504F3u);             // float32(sqrt(2))
    return sqrt2 * erfinv_xla_f32(u);
}

// Geometry: (4,100,512,512) f32. Channel = 65536 f4. Group = 10 channels
// (cb0 = grp*10 is noise; +1..+9 are copies). Tile = 2048 f4 => 32 tiles/group,
// 40 groups => 1280 blocks = 5/CU exactly, single co-resident pass.
constexpr uint32_t NBLOCKS = 40u * 32u;

__global__ __launch_bounds__(256, 5) void random_masking_kernel(
        const f32x4* __restrict__ in, f32x4* __restrict__ out) {
    const uint32_t bid   = blockIdx.x;
    const uint32_t grp   = bid >> 5;                   // 0..39  (== b*10 + s)
    const uint32_t tile  = bid & 31u;
    const uint32_t cb0   = grp * 10u;                  // noise channel (b*100+c)
    const uint32_t off   = (tile << 11) + threadIdx.x; // f4 offset in channel
    const uint32_t jch   = grp << 18;                  // noise-array channel base
    const uint32_t base0 = (cb0 << 16) + off;

    for (uint32_t ch = 1; ch <= 9; ++ch) {
        const f32x4* src = in  + base0 + (ch << 16);
        f32x4*       dst = out + base0 + (ch << 16);

        // issue 8 independent nt loads for this copy channel
        f32x4 v[8];
#pragma unroll
        for (int k = 0; k < 8; ++k)
            v[k] = __builtin_nontemporal_load(src + k * 256);

        // one noise f4 per iteration (8 total over ch=1..8), overlapping the
        // outstanding loads — pure VALU, no memory dependence
        if (ch <= 8) {
            const uint32_t q = ch - 1;
            const uint32_t j = jch + ((off + q * 256u) << 2);
            f32x4 o;
#pragma unroll
            for (int e = 0; e < 4; ++e) {
                uint32_t y0, y1;
                threefry2x32_key01(0u, j + (uint32_t)e, y0, y1);
                o[e] = bits_to_normal(y0 ^ y1);
            }
            __builtin_nontemporal_store(o, out + base0 + q * 256);
        }

        // store the copied channel (compiler waits vmcnt here, after the VALU)
#pragma unroll
        for (int k = 0; k < 8; ++k)
            __builtin_nontemporal_store(v[k], dst + k * 256);
    }
}

extern "C" void kernel_launch(void* const* d_in, const int* in_sizes, int n_in,
                              void* d_out, int out_size, void* d_ws, size_t ws_size,
                              hipStream_t stream) {
    const f32x4* in = reinterpret_cast<const f32x4*>(d_in[0]);
    f32x4* out = reinterpret_cast<f32x4*>(d_out);
    random_masking_kernel<<<NBLOCKS, 256, 0, stream>>>(in, out);
}